// Round 1
// baseline (158.443 us; speedup 1.0000x reference)
//
#include <hip/hip_runtime.h>

#define TEMP 0.7f
#define LOG2E 1.4426950408889634f
#define LN2 0.6931471805599453f
#define NPIX 8192
#define CDIM 128
// sqrt(LOG2E / TEMP): fold exp2-conversion + temperature into bf16 operands
#define FSCALE 1.4356161f

typedef __bf16 v8bf __attribute__((ext_vector_type(8)));
typedef float f32x4 __attribute__((ext_vector_type(4)));

// workspace layout (float offsets)
#define OFF_ROWSUM 0            // 8192 floats
#define OFF_DIAG   8192         // 8192 floats
#define OFF_G      16384        // 4*128 floats
#define OFF_COUNTS 16896        // int[4]
#define OFF_ACC    16900        // 1 float
#define OFF_ZERON  16960        // zero the first OFF_ZERON floats
#define OFF_F32    16960        // NPIX*CDIM floats
#define OFF_SWF    (16960 + NPIX*CDIM)  // NPIX*CDIM bf16 (= NPIX*CDIM/2 floats)

__device__ __forceinline__ int label_index(int n) {
    // n = b'*1024 + p ; b' < 4 -> view 0, else view 1 ; labels[B][V][H][W]
    const int bp = n >> 10, p = n & 1023;
    const int b = bp & 3, v = bp >> 2;
    return ((b * 2 + v) << 10) + p;
}

__global__ __launch_bounds__(256) void k0_zero(float* __restrict__ w) {
    const int i = blockIdx.x * 256 + threadIdx.x;
    if (i < OFF_ZERON) w[i] = 0.0f;
}

// Build fp32 [N][C], swizzled bf16 fragment layout, and diag = |f|^2/TEMP
__global__ __launch_bounds__(128) void k1_build(
    const float* __restrict__ feats, float* __restrict__ f32t,
    v8bf* __restrict__ swf, float* __restrict__ diag)
{
    const int n = blockIdx.x;
    const int c = threadIdx.x;
    const int bp = n >> 10, p = n & 1023;
    const int b = bp & 3, v = bp >> 2;
    const float f = feats[(((b * 2 + v) * CDIM + c) << 10) + p];
    f32t[n * CDIM + c] = f;

    __shared__ float red[128];
    __shared__ __bf16 lb[128];
    lb[c] = (__bf16)(f * FSCALE);
    red[c] = f * f;
    __syncthreads();
    for (int s = 64; s > 0; s >>= 1) {
        if (c < s) red[c] += red[c + s];
        __syncthreads();
    }
    if (c == 0) diag[n] = red[0] * (1.0f / TEMP);

    // swizzled write: frag index (ct*4+kk)*64 + q*16 + r holds
    // F[ct*16 + r][kk*32 + q*8 + j], j=0..7
    if (c < 16) {
        const int kk = c >> 2, q = c & 3;
        const int ct = n >> 4, r = n & 15;
        v8bf val;
#pragma unroll
        for (int j = 0; j < 8; j++) val[j] = lb[kk * 32 + q * 8 + j];
        swf[(ct * 4 + kk) * 64 + q * 16 + r] = val;
    }
}

// Per-class feature sums G[4][C] and label counts
__global__ __launch_bounds__(128) void k2_classsum(
    const float* __restrict__ f32t, const int* __restrict__ labels,
    float* __restrict__ G, int* __restrict__ counts)
{
    const int c = threadIdx.x;
    const int n0 = blockIdx.x * 64;
    float a0 = 0.f, a1 = 0.f, a2 = 0.f, a3 = 0.f;
    int l0 = 0, l1 = 0, l2 = 0, l3 = 0;
    for (int i = 0; i < 64; i++) {
        const int n = n0 + i;
        const int lab = labels[label_index(n)];
        const float f = f32t[n * CDIM + c];
        a0 += (lab == 0) ? f : 0.f;
        a1 += (lab == 1) ? f : 0.f;
        a2 += (lab == 2) ? f : 0.f;
        a3 += (lab == 3) ? f : 0.f;
        if (c == 0) {
            l0 += (lab == 0); l1 += (lab == 1);
            l2 += (lab == 2); l3 += (lab == 3);
        }
    }
    atomicAdd(&G[0 * CDIM + c], a0);
    atomicAdd(&G[1 * CDIM + c], a1);
    atomicAdd(&G[2 * CDIM + c], a2);
    atomicAdd(&G[3 * CDIM + c], a3);
    if (c == 0) {
        atomicAdd(&counts[0], l0); atomicAdd(&counts[1], l1);
        atomicAdd(&counts[2], l2); atomicAdd(&counts[3], l3);
    }
}

// Fused S = F F^T (bf16 MFMA) + exp2 row-sum.
// Block = 4 waves; each wave owns 32 rows (two 16-row MFMA tiles).
// Grid = 64 row-blocks x 8 col-chunks; rowsum accumulated via atomicAdd.
__global__ __launch_bounds__(256) void k3_gemm_expsum(
    const v8bf* __restrict__ swf, float* __restrict__ rowsum)
{
    const int lane = threadIdx.x & 63;
    const int wave = threadIdx.x >> 6;
    const int rowblk = blockIdx.x & 63;
    const int colchunk = blockIdx.x >> 6;
    const int rowbase = rowblk * 128 + wave * 32;
    const int rt0 = rowbase >> 4;

    v8bf a0[4], a1[4];
#pragma unroll
    for (int kk = 0; kk < 4; kk++) a0[kk] = swf[(rt0 * 4 + kk) * 64 + lane];
#pragma unroll
    for (int kk = 0; kk < 4; kk++) a1[kk] = swf[((rt0 + 1) * 4 + kk) * 64 + lane];

    float rs0[4] = {0.f, 0.f, 0.f, 0.f};
    float rs1[4] = {0.f, 0.f, 0.f, 0.f};

    const int ct0 = colchunk * 64;        // 1024 cols / 16
    for (int ct = ct0; ct < ct0 + 64; ++ct) {
        const v8bf b0 = swf[(ct * 4 + 0) * 64 + lane];
        const v8bf b1 = swf[(ct * 4 + 1) * 64 + lane];
        const v8bf b2 = swf[(ct * 4 + 2) * 64 + lane];
        const v8bf b3 = swf[(ct * 4 + 3) * 64 + lane];
        f32x4 acc0 = {0.f, 0.f, 0.f, 0.f};
        f32x4 acc1 = {0.f, 0.f, 0.f, 0.f};
        acc0 = __builtin_amdgcn_mfma_f32_16x16x32_bf16(a0[0], b0, acc0, 0, 0, 0);
        acc0 = __builtin_amdgcn_mfma_f32_16x16x32_bf16(a0[1], b1, acc0, 0, 0, 0);
        acc0 = __builtin_amdgcn_mfma_f32_16x16x32_bf16(a0[2], b2, acc0, 0, 0, 0);
        acc0 = __builtin_amdgcn_mfma_f32_16x16x32_bf16(a0[3], b3, acc0, 0, 0, 0);
        acc1 = __builtin_amdgcn_mfma_f32_16x16x32_bf16(a1[0], b0, acc1, 0, 0, 0);
        acc1 = __builtin_amdgcn_mfma_f32_16x16x32_bf16(a1[1], b1, acc1, 0, 0, 0);
        acc1 = __builtin_amdgcn_mfma_f32_16x16x32_bf16(a1[2], b2, acc1, 0, 0, 0);
        acc1 = __builtin_amdgcn_mfma_f32_16x16x32_bf16(a1[3], b3, acc1, 0, 0, 0);
        // acc already = S * log2(e) thanks to FSCALE folding
#pragma unroll
        for (int r = 0; r < 4; r++) {
            rs0[r] += __builtin_amdgcn_exp2f(acc0[r]);
            rs1[r] += __builtin_amdgcn_exp2f(acc1[r]);
        }
    }

    // reduce across the 16 lanes of each C/D column group
#pragma unroll
    for (int m = 1; m < 16; m <<= 1) {
#pragma unroll
        for (int r = 0; r < 4; r++) {
            rs0[r] += __shfl_xor(rs0[r], m, 64);
            rs1[r] += __shfl_xor(rs1[r], m, 64);
        }
    }
    if ((lane & 15) == 0) {
        const int g = lane >> 4;
#pragma unroll
        for (int r = 0; r < 4; r++) {
            atomicAdd(&rowsum[rowbase + g * 4 + r], rs0[r]);
            atomicAdd(&rowsum[rowbase + 16 + g * 4 + r], rs1[r]);
        }
    }
}

// Per-anchor loss: log(den) - num/cnt, summed into acc
__global__ __launch_bounds__(64) void k4_loss(
    const float* __restrict__ f32t, const int* __restrict__ labels,
    const float* __restrict__ G, const int* __restrict__ counts,
    const float* __restrict__ diag, const float* __restrict__ rowsum,
    float* __restrict__ acc)
{
    const int n = blockIdx.x;
    const int lane = threadIdx.x;
    const int lab = labels[label_index(n)];
    const float* g = G + lab * CDIM;
    float dot = f32t[n * CDIM + lane] * g[lane]
              + f32t[n * CDIM + 64 + lane] * g[64 + lane];
#pragma unroll
    for (int m = 1; m < 64; m <<= 1) dot += __shfl_xor(dot, m, 64);
    if (lane == 0 && lab != 0) {
        const float d = diag[n];
        const float num = dot * (1.0f / TEMP) - d;
        const float den = rowsum[n] - __builtin_amdgcn_exp2f(d * LOG2E);
        const float cnt = (float)(counts[lab] - 1);
        const float loss = __builtin_amdgcn_logf(den) * LN2 - num / cnt;
        atomicAdd(acc, loss);
    }
}

__global__ void k5_final(const float* __restrict__ acc,
                         const int* __restrict__ counts,
                         float* __restrict__ out)
{
    const int nv = NPIX - counts[0];
    out[0] = (nv > 0) ? acc[0] / (float)nv : 0.0f;
}

extern "C" void kernel_launch(void* const* d_in, const int* in_sizes, int n_in,
                              void* d_out, int out_size, void* d_ws, size_t ws_size,
                              hipStream_t stream) {
    const float* feats = (const float*)d_in[0];
    const int* labels = (const int*)d_in[1];
    float* out = (float*)d_out;
    float* W = (float*)d_ws;

    float* rowsum = W + OFF_ROWSUM;
    float* diag   = W + OFF_DIAG;
    float* G      = W + OFF_G;
    int*   counts = (int*)(W + OFF_COUNTS);
    float* acc    = W + OFF_ACC;
    float* f32t   = W + OFF_F32;
    v8bf*  swf    = (v8bf*)(W + OFF_SWF);

    k0_zero<<<(OFF_ZERON + 255) / 256, 256, 0, stream>>>(W);
    k1_build<<<NPIX, 128, 0, stream>>>(feats, f32t, swf, diag);
    k2_classsum<<<NPIX / 64, 128, 0, stream>>>(f32t, labels, G, counts);
    k3_gemm_expsum<<<64 * 8, 256, 0, stream>>>(swf, rowsum);
    k4_loss<<<NPIX, 64, 0, stream>>>(f32t, labels, G, counts, diag, rowsum, acc);
    k5_final<<<1, 1, 0, stream>>>(acc, counts, out);
}

// Round 2
// 68.860 us; speedup vs baseline: 2.3010x; 2.3010x over previous
//
#include <hip/hip_runtime.h>

#define TEMP 0.7f
#define LOG2E 1.4426950408889634f
#define LN2 0.6931471805599453f
#define NPIX 8192
#define CDIM 128
// sqrt(LOG2E / TEMP): fold exp2-conversion + temperature into bf16 operands
#define FSCALE 1.4356161f
// exp(1/TEMP) = exp(diag) since features are L2-normalized (|F|^2 == 1)
#define EXPDIAG 4.1727352f

typedef __bf16 v8bf __attribute__((ext_vector_type(8)));
typedef float f32x4 __attribute__((ext_vector_type(4)));

// workspace layout (float offsets)
#define OFF_ROWSUM 0            // 8192 floats
#define OFF_G      8192         // 4*128 floats
#define OFF_COUNTS 8704         // int[4]
#define OFF_ACC    8708         // 1 float
#define OFF_ZERON  8712         // zero the first OFF_ZERON floats
#define OFF_F32    8960         // NPIX*CDIM floats
#define OFF_SWF    (8960 + NPIX*CDIM)  // NPIX*CDIM bf16

__global__ __launch_bounds__(256) void k0_zero(float* __restrict__ w) {
    const int i = blockIdx.x * 256 + threadIdx.x;
    if (i < OFF_ZERON) w[i] = 0.0f;
}

// Transpose-build: coalesced feats reads -> LDS tile (128c x 64p, pad 65),
// then emit f32t [n][c], swizzled bf16 MFMA fragments, class sums G, counts.
__global__ __launch_bounds__(256) void k1_build(
    const float* __restrict__ feats, const int* __restrict__ labels,
    float* __restrict__ f32t, v8bf* __restrict__ swf,
    float* __restrict__ G, int* __restrict__ counts)
{
    __shared__ float lds[128][65];
    __shared__ int lab_l[64];
    __shared__ float cs[2][4][128];

    const int t = threadIdx.x;
    const int lane = t & 63, cg = t >> 6;
    const int bp = blockIdx.x >> 4;   // b' = row-block in concat order, 0..7
    const int pc = blockIdx.x & 15;   // 64-pixel chunk
    const int b = bp & 3, v = bp >> 2;
    const int bv = b * 2 + v;         // index into feats/labels batch dim
    const int p0 = pc * 64;
    const int nbase = bp * 1024 + p0;

    // coalesced load: each wave reads 256B rows of a fixed channel
    const float* src = feats + (size_t)bv * CDIM * 1024 + p0;
#pragma unroll
    for (int i = 0; i < 32; i++) {
        const int c = cg * 32 + i;
        lds[c][lane] = src[c * 1024 + lane];
    }
    // labels + counts (wave 0 only; t == lane there)
    if (t < 64) {
        const int lab = labels[bv * 1024 + p0 + t];
        lab_l[t] = lab;
#pragma unroll
        for (int k = 0; k < 4; k++) {
            unsigned long long m = __ballot(lab == k);
            if (t == 0) atomicAdd(&counts[k], (int)__popcll(m));
        }
    }
    __syncthreads();

    // f32t [n][c] writes, coalesced along c (2 rows per pass)
    {
        const int cw = t & 127, h = t >> 7;
        float* dst = f32t + (size_t)nbase * CDIM + cw;
#pragma unroll
        for (int i = 0; i < 32; i++) {
            const int nl = h + 2 * i;
            dst[nl * CDIM] = lds[cw][nl];
        }
    }

    // per-class partial sums over this block's 64 pixels
    {
        const int cw = t & 127, h = t >> 7;
        float s0 = 0.f, s1 = 0.f, s2 = 0.f, s3 = 0.f;
#pragma unroll
        for (int i = 0; i < 32; i++) {
            const int nl = h * 32 + i;
            const int lab = lab_l[nl];
            const float f = lds[cw][nl];
            s0 += (lab == 0) ? f : 0.f;
            s1 += (lab == 1) ? f : 0.f;
            s2 += (lab == 2) ? f : 0.f;
            s3 += (lab == 3) ? f : 0.f;
        }
        cs[h][0][cw] = s0; cs[h][1][cw] = s1;
        cs[h][2][cw] = s2; cs[h][3][cw] = s3;
    }
    __syncthreads();
    if (t < 128) {
#pragma unroll
        for (int k = 0; k < 4; k++)
            atomicAdd(&G[k * CDIM + t], cs[0][k][t] + cs[1][k][t]);
    }

    // swizzled bf16 fragment writes:
    // frag (ctg*4+kk), element q*16+r holds F[ctg*16+r][kk*32+q*8+j]*FSCALE
    #pragma unroll
    for (int i = 0; i < 4; i++) {
        const int slot = i * 256 + t;
        const int f = slot >> 6, l = slot & 63;
        const int ctl = f >> 2, kk = f & 3;
        const int q = l >> 4, r = l & 15;
        const int nl = ctl * 16 + r;
        const int c0 = kk * 32 + q * 8;
        v8bf val;
#pragma unroll
        for (int j = 0; j < 8; j++) val[j] = (__bf16)(lds[c0 + j][nl] * FSCALE);
        const int ctg = (nbase >> 4) + ctl;
        swf[(ctg * 4 + kk) * 64 + l] = val;
    }
}

// Fused S = F F^T (bf16 MFMA) + exp2 row-sum.
// Block = 4 waves; each wave owns 32 rows (two 16-row MFMA tiles).
// Grid = 64 row-blocks x 8 col-chunks; rowsum accumulated via atomicAdd.
__global__ __launch_bounds__(256) void k3_gemm_expsum(
    const v8bf* __restrict__ swf, float* __restrict__ rowsum)
{
    const int lane = threadIdx.x & 63;
    const int wave = threadIdx.x >> 6;
    const int rowblk = blockIdx.x & 63;
    const int colchunk = blockIdx.x >> 6;
    const int rowbase = rowblk * 128 + wave * 32;
    const int rt0 = rowbase >> 4;

    v8bf a0[4], a1[4];
#pragma unroll
    for (int kk = 0; kk < 4; kk++) a0[kk] = swf[(rt0 * 4 + kk) * 64 + lane];
#pragma unroll
    for (int kk = 0; kk < 4; kk++) a1[kk] = swf[((rt0 + 1) * 4 + kk) * 64 + lane];

    float rs0[4] = {0.f, 0.f, 0.f, 0.f};
    float rs1[4] = {0.f, 0.f, 0.f, 0.f};

    const int ct0 = colchunk * 64;        // 1024 cols / 16
    for (int ct = ct0; ct < ct0 + 64; ++ct) {
        const v8bf b0 = swf[(ct * 4 + 0) * 64 + lane];
        const v8bf b1 = swf[(ct * 4 + 1) * 64 + lane];
        const v8bf b2 = swf[(ct * 4 + 2) * 64 + lane];
        const v8bf b3 = swf[(ct * 4 + 3) * 64 + lane];
        f32x4 acc0 = {0.f, 0.f, 0.f, 0.f};
        f32x4 acc1 = {0.f, 0.f, 0.f, 0.f};
        acc0 = __builtin_amdgcn_mfma_f32_16x16x32_bf16(a0[0], b0, acc0, 0, 0, 0);
        acc0 = __builtin_amdgcn_mfma_f32_16x16x32_bf16(a0[1], b1, acc0, 0, 0, 0);
        acc0 = __builtin_amdgcn_mfma_f32_16x16x32_bf16(a0[2], b2, acc0, 0, 0, 0);
        acc0 = __builtin_amdgcn_mfma_f32_16x16x32_bf16(a0[3], b3, acc0, 0, 0, 0);
        acc1 = __builtin_amdgcn_mfma_f32_16x16x32_bf16(a1[0], b0, acc1, 0, 0, 0);
        acc1 = __builtin_amdgcn_mfma_f32_16x16x32_bf16(a1[1], b1, acc1, 0, 0, 0);
        acc1 = __builtin_amdgcn_mfma_f32_16x16x32_bf16(a1[2], b2, acc1, 0, 0, 0);
        acc1 = __builtin_amdgcn_mfma_f32_16x16x32_bf16(a1[3], b3, acc1, 0, 0, 0);
        // acc already = S * log2(e) thanks to FSCALE folding
#pragma unroll
        for (int r = 0; r < 4; r++) {
            rs0[r] += __builtin_amdgcn_exp2f(acc0[r]);
            rs1[r] += __builtin_amdgcn_exp2f(acc1[r]);
        }
    }

    // reduce across the 16 lanes of each C/D column group
#pragma unroll
    for (int m = 1; m < 16; m <<= 1) {
#pragma unroll
        for (int r = 0; r < 4; r++) {
            rs0[r] += __shfl_xor(rs0[r], m, 64);
            rs1[r] += __shfl_xor(rs1[r], m, 64);
        }
    }
    if ((lane & 15) == 0) {
        const int g = lane >> 4;
#pragma unroll
        for (int r = 0; r < 4; r++) {
            atomicAdd(&rowsum[rowbase + g * 4 + r], rs0[r]);
            atomicAdd(&rowsum[rowbase + 16 + g * 4 + r], rs1[r]);
        }
    }
}

// Per-anchor loss. 128 blocks x 4 waves; each wave handles 16 anchors,
// accumulates in-register; ONE atomicAdd per block (128 total, was 6144).
__global__ __launch_bounds__(256) void k4_loss(
    const float* __restrict__ f32t, const int* __restrict__ labels,
    const float* __restrict__ G, const int* __restrict__ counts,
    const float* __restrict__ rowsum, float* __restrict__ acc)
{
    const int t = threadIdx.x, lane = t & 63, w = t >> 6;
    const int wid = blockIdx.x * 4 + w;      // 0..511
    float wsum = 0.f;
    for (int a = 0; a < 16; a++) {
        const int n = wid * 16 + a;
        const int bp = n >> 10, p = n & 1023;
        const int lab = labels[(((bp & 3) * 2 + (bp >> 2)) << 10) + p];
        const float* fr = f32t + (size_t)n * CDIM;
        const float* g = G + lab * CDIM;
        float dot = fr[lane] * g[lane] + fr[lane + 64] * g[lane + 64];
#pragma unroll
        for (int m = 1; m < 64; m <<= 1) dot += __shfl_xor(dot, m, 64);
        if (lane == 0 && lab != 0) {
            const float num = (dot - 1.0f) * (1.0f / TEMP);
            const float den = rowsum[n] - EXPDIAG;
            const float cnt = (float)(counts[lab] - 1);
            wsum += __builtin_amdgcn_logf(den) * LN2 - num / cnt;
        }
    }
    __shared__ float red[4];
    if (lane == 0) red[w] = wsum;
    __syncthreads();
    if (t == 0) atomicAdd(acc, red[0] + red[1] + red[2] + red[3]);
}

__global__ void k5_final(const float* __restrict__ acc,
                         const int* __restrict__ counts,
                         float* __restrict__ out)
{
    const int nv = NPIX - counts[0];
    out[0] = (nv > 0) ? acc[0] / (float)nv : 0.0f;
}

extern "C" void kernel_launch(void* const* d_in, const int* in_sizes, int n_in,
                              void* d_out, int out_size, void* d_ws, size_t ws_size,
                              hipStream_t stream) {
    const float* feats = (const float*)d_in[0];
    const int* labels = (const int*)d_in[1];
    float* out = (float*)d_out;
    float* W = (float*)d_ws;

    float* rowsum = W + OFF_ROWSUM;
    float* G      = W + OFF_G;
    int*   counts = (int*)(W + OFF_COUNTS);
    float* acc    = W + OFF_ACC;
    float* f32t   = W + OFF_F32;
    v8bf*  swf    = (v8bf*)(W + OFF_SWF);

    k0_zero<<<(OFF_ZERON + 255) / 256, 256, 0, stream>>>(W);
    k1_build<<<128, 256, 0, stream>>>(feats, labels, f32t, swf, G, counts);
    k3_gemm_expsum<<<64 * 8, 256, 0, stream>>>(swf, rowsum);
    k4_loss<<<128, 256, 0, stream>>>(f32t, labels, G, counts, rowsum, acc);
    k5_final<<<1, 1, 0, stream>>>(acc, counts, out);
}

// Round 3
// 47.272 us; speedup vs baseline: 3.3518x; 1.4567x over previous
//
#include <hip/hip_runtime.h>

#define TEMP 0.7f
#define LOG2E 1.4426950408889634f
#define LN2 0.6931471805599453f
#define NPIX 8192
#define CDIM 128
// sqrt(LOG2E / TEMP): fold exp2-conversion + temperature into bf16 operands
#define FSCALE 1.4356161f
// exp(1/TEMP) = exp(diag) since features are L2-normalized (|F|^2 == 1)
#define EXPDIAG 4.1727352f

typedef __bf16 v8bf __attribute__((ext_vector_type(8)));
typedef float f32x4 __attribute__((ext_vector_type(4)));

// workspace layout (float offsets)
#define OFF_ROWSUM 0            // 8192 floats
#define OFF_G      8192         // 4*128 floats
#define OFF_COUNTS 8704         // int[4]
#define OFF_ACC    8708         // 1 float
#define OFF_ZERON  8712         // zero the first OFF_ZERON floats
#define OFF_SWF    8960         // NPIX*CDIM bf16

__global__ __launch_bounds__(256) void k0_zero(float* __restrict__ w) {
    const int i = blockIdx.x * 256 + threadIdx.x;
    if (i < OFF_ZERON) w[i] = 0.0f;
}

// Transpose-build: coalesced feats reads -> LDS tile (128c x 64p, pad 65),
// then emit swizzled bf16 MFMA fragments, class sums G, counts.
__global__ __launch_bounds__(256) void k1_build(
    const float* __restrict__ feats, const int* __restrict__ labels,
    v8bf* __restrict__ swf, float* __restrict__ G, int* __restrict__ counts)
{
    __shared__ float lds[128][65];
    __shared__ int lab_l[64];
    __shared__ float cs[2][4][128];

    const int t = threadIdx.x;
    const int lane = t & 63, cg = t >> 6;
    const int bp = blockIdx.x >> 4;   // b' = row-block in concat order, 0..7
    const int pc = blockIdx.x & 15;   // 64-pixel chunk
    const int b = bp & 3, v = bp >> 2;
    const int bv = b * 2 + v;         // index into feats/labels batch dim
    const int p0 = pc * 64;
    const int nbase = bp * 1024 + p0;

    // coalesced load: each wave reads 256B rows of a fixed channel
    const float* src = feats + (size_t)bv * CDIM * 1024 + p0;
#pragma unroll
    for (int i = 0; i < 32; i++) {
        const int c = cg * 32 + i;
        lds[c][lane] = src[c * 1024 + lane];
    }
    // labels + counts (wave 0 only; t == lane there)
    if (t < 64) {
        const int lab = labels[bv * 1024 + p0 + t];
        lab_l[t] = lab;
#pragma unroll
        for (int k = 0; k < 4; k++) {
            unsigned long long m = __ballot(lab == k);
            if (t == 0) atomicAdd(&counts[k], (int)__popcll(m));
        }
    }
    __syncthreads();

    // per-class partial sums over this block's 64 pixels
    {
        const int cw = t & 127, h = t >> 7;
        float s0 = 0.f, s1 = 0.f, s2 = 0.f, s3 = 0.f;
#pragma unroll
        for (int i = 0; i < 32; i++) {
            const int nl = h * 32 + i;
            const int lab = lab_l[nl];
            const float f = lds[cw][nl];
            s0 += (lab == 0) ? f : 0.f;
            s1 += (lab == 1) ? f : 0.f;
            s2 += (lab == 2) ? f : 0.f;
            s3 += (lab == 3) ? f : 0.f;
        }
        cs[h][0][cw] = s0; cs[h][1][cw] = s1;
        cs[h][2][cw] = s2; cs[h][3][cw] = s3;
    }
    __syncthreads();
    if (t < 128) {
#pragma unroll
        for (int k = 0; k < 4; k++)
            atomicAdd(&G[k * CDIM + t], cs[0][k][t] + cs[1][k][t]);
    }

    // swizzled bf16 fragment writes:
    // frag (ctg*4+kk), element q*16+r holds F[ctg*16+r][kk*32+q*8+j]*FSCALE
    #pragma unroll
    for (int i = 0; i < 4; i++) {
        const int slot = i * 256 + t;
        const int f = slot >> 6, l = slot & 63;
        const int ctl = f >> 2, kk = f & 3;
        const int q = l >> 4, r = l & 15;
        const int nl = ctl * 16 + r;
        const int c0 = kk * 32 + q * 8;
        v8bf val;
#pragma unroll
        for (int j = 0; j < 8; j++) val[j] = (__bf16)(lds[c0 + j][nl] * FSCALE);
        const int ctg = (nbase >> 4) + ctl;
        swf[(ctg * 4 + kk) * 64 + l] = val;
    }
}

// Fused S = F F^T (bf16 MFMA) + exp2 row-sum.
// Block = 4 waves; each wave owns 64 rows (four 16-row MFMA tiles, A-frags
// resident in 64 VGPRs -> 4x register reuse of each B fragment).
// Grid = 32 row-blocks x 32 col-chunks = 1024 blocks = 4096 waves (4/SIMD).
__global__ __launch_bounds__(256, 4) void k3_gemm_expsum(
    const v8bf* __restrict__ swf, float* __restrict__ rowsum)
{
    const int lane = threadIdx.x & 63;
    const int wave = threadIdx.x >> 6;
    const int rowblk = blockIdx.x & 31;    // 256 rows each
    const int colchunk = blockIdx.x >> 5;  // 256 cols each
    const int rowbase = rowblk * 256 + wave * 64;
    const int rt0 = rowbase >> 4;

    v8bf a[4][4];
#pragma unroll
    for (int tt = 0; tt < 4; tt++)
#pragma unroll
        for (int kk = 0; kk < 4; kk++)
            a[tt][kk] = swf[((rt0 + tt) * 4 + kk) * 64 + lane];

    float rs[4][4];
#pragma unroll
    for (int tt = 0; tt < 4; tt++)
#pragma unroll
        for (int r = 0; r < 4; r++) rs[tt][r] = 0.f;

    const int ct0 = colchunk * 16;         // 16 col-tiles of 16
    for (int ct = ct0; ct < ct0 + 16; ++ct) {
        const v8bf b0 = swf[(ct * 4 + 0) * 64 + lane];
        const v8bf b1 = swf[(ct * 4 + 1) * 64 + lane];
        const v8bf b2 = swf[(ct * 4 + 2) * 64 + lane];
        const v8bf b3 = swf[(ct * 4 + 3) * 64 + lane];
#pragma unroll
        for (int tt = 0; tt < 4; tt++) {
            f32x4 acc = {0.f, 0.f, 0.f, 0.f};
            acc = __builtin_amdgcn_mfma_f32_16x16x32_bf16(a[tt][0], b0, acc, 0, 0, 0);
            acc = __builtin_amdgcn_mfma_f32_16x16x32_bf16(a[tt][1], b1, acc, 0, 0, 0);
            acc = __builtin_amdgcn_mfma_f32_16x16x32_bf16(a[tt][2], b2, acc, 0, 0, 0);
            acc = __builtin_amdgcn_mfma_f32_16x16x32_bf16(a[tt][3], b3, acc, 0, 0, 0);
            // acc already = S * log2(e) thanks to FSCALE folding
#pragma unroll
            for (int r = 0; r < 4; r++)
                rs[tt][r] += __builtin_amdgcn_exp2f(acc[r]);
        }
    }

    // reduce across the 16 lanes of each C/D column group
#pragma unroll
    for (int m = 1; m < 16; m <<= 1)
#pragma unroll
        for (int tt = 0; tt < 4; tt++)
#pragma unroll
            for (int r = 0; r < 4; r++)
                rs[tt][r] += __shfl_xor(rs[tt][r], m, 64);

    if ((lane & 15) == 0) {
        const int g = lane >> 4;
#pragma unroll
        for (int tt = 0; tt < 4; tt++)
#pragma unroll
            for (int r = 0; r < 4; r++)
                atomicAdd(&rowsum[rowbase + tt * 16 + g * 4 + r], rs[tt][r]);
    }
}

// Per-anchor loss. Block = 4 waves over 64 anchors (one anchor per lane,
// p-coalesced feats reads); each wave covers 32 channels; LDS combine.
__global__ __launch_bounds__(256) void k4_loss(
    const float* __restrict__ feats, const int* __restrict__ labels,
    const float* __restrict__ G, const int* __restrict__ counts,
    const float* __restrict__ rowsum, float* __restrict__ acc)
{
    __shared__ float pd[4][64];
    const int t = threadIdx.x, lane = t & 63, w = t >> 6;
    const int n0 = blockIdx.x * 64;
    const int bp = n0 >> 10, p0 = n0 & 1023;
    const int bv = ((bp & 3) << 1) + (bp >> 2);
    const int p = p0 + lane;
    const int lab = labels[(bv << 10) + p];

    const float* src = feats + (((size_t)bv * CDIM + w * 32) << 10) + p;
    const float* g0p = G + w * 32;
    float dot = 0.f;
#pragma unroll 8
    for (int c = 0; c < 32; ++c) {
        const float f = src[(size_t)c << 10];
        const float g0 = g0p[c], g1 = g0p[CDIM + c];
        const float g2 = g0p[2 * CDIM + c], g3 = g0p[3 * CDIM + c];
        const float g = (lab == 1) ? g1 : (lab == 2) ? g2 : (lab == 3) ? g3 : g0;
        dot += f * g;
    }
    pd[w][lane] = dot;
    __syncthreads();
    if (w == 0) {
        const float d = pd[0][lane] + pd[1][lane] + pd[2][lane] + pd[3][lane];
        float loss = 0.f;
        if (lab != 0) {
            const float num = (d - 1.0f) * (1.0f / TEMP);
            const float den = rowsum[n0 + lane] - EXPDIAG;
            const float cnt = (float)(counts[lab] - 1);
            loss = __builtin_amdgcn_logf(den) * LN2 - num / cnt;
        }
#pragma unroll
        for (int m = 1; m < 64; m <<= 1) loss += __shfl_xor(loss, m, 64);
        if (lane == 0) atomicAdd(acc, loss);
    }
}

__global__ void k5_final(const float* __restrict__ acc,
                         const int* __restrict__ counts,
                         float* __restrict__ out)
{
    const int nv = NPIX - counts[0];
    out[0] = (nv > 0) ? acc[0] / (float)nv : 0.0f;
}

extern "C" void kernel_launch(void* const* d_in, const int* in_sizes, int n_in,
                              void* d_out, int out_size, void* d_ws, size_t ws_size,
                              hipStream_t stream) {
    const float* feats = (const float*)d_in[0];
    const int* labels = (const int*)d_in[1];
    float* out = (float*)d_out;
    float* W = (float*)d_ws;

    float* rowsum = W + OFF_ROWSUM;
    float* G      = W + OFF_G;
    int*   counts = (int*)(W + OFF_COUNTS);
    float* acc    = W + OFF_ACC;
    v8bf*  swf    = (v8bf*)(W + OFF_SWF);

    k0_zero<<<(OFF_ZERON + 255) / 256, 256, 0, stream>>>(W);
    k1_build<<<128, 256, 0, stream>>>(feats, labels, swf, G, counts);
    k3_gemm_expsum<<<32 * 32, 256, 0, stream>>>(swf, rowsum);
    k4_loss<<<128, 256, 0, stream>>>(feats, labels, G, counts, rowsum, acc);
    k5_final<<<1, 1, 0, stream>>>(acc, counts, out);
}